// Round 1
// baseline (1338.102 us; speedup 1.0000x reference)
//
#include <hip/hip_runtime.h>

#define N_Q 8192
#define N_K 16384
#define C_DIM 256
#define TQ 64
#define TK 64
#define N_CHUNKS 8
#define KCHUNK (N_K / N_CHUNKS) /* 2048 */

// ---------------------------------------------------------------------------
// e_sq[k] = sum_c codebook[k][c]^2  (fp32; order-insensitive for argmin --
// e_sq is far below ulp(x_sq)/2 so it only matters at rounding midpoints)
// ---------------------------------------------------------------------------
__global__ __launch_bounds__(256) void vq_esq_kernel(const float* __restrict__ cb,
                                                     float* __restrict__ esq) {
  int k = blockIdx.x * blockDim.x + threadIdx.x;
  if (k >= N_K) return;
  const float4* row = reinterpret_cast<const float4*>(cb + (size_t)k * C_DIM);
  float s = 0.f;
#pragma unroll 8
  for (int c4 = 0; c4 < C_DIM / 4; ++c4) {
    float4 v = row[c4];
    s = fmaf(v.x, v.x, s);
    s = fmaf(v.y, v.y, s);
    s = fmaf(v.z, v.z, s);
    s = fmaf(v.w, v.w, s);
  }
  esq[k] = s;
}

// ---------------------------------------------------------------------------
// Main kernel: one block = 64 queries x 2048 codebook entries.
//   x tile in LDS c-major (direct from hidden's (b,c,hw) layout, coalesced),
//   e tile in LDS k-major. 256 threads = 16(q-groups) x 16(k-groups),
//   register blocking 4x4. Dot product: STRICT sequential fmaf over c
//   (replicates CPU BLAS sgemm per-element accumulation order).
//   d = fl(fl(x_sq + e_sq) - 2*dot)  -- exact np fp32 semantics.
//   Tie-break = first (lowest) index, like np.argmin.
// ---------------------------------------------------------------------------
__global__ __launch_bounds__(256) void vq_main_kernel(
    const float* __restrict__ hidden, const float* __restrict__ cb,
    const float* __restrict__ esq, float* __restrict__ ws_d,
    int* __restrict__ ws_k) {
  __shared__ __align__(16) float xs[C_DIM][TQ + 4];   // c-major, stride 68
  __shared__ __align__(16) float es[TK][C_DIM + 4];   // k-major, stride 260
  __shared__ float xsq_part[4][TQ];
  __shared__ float xsq[TQ];
  __shared__ float red_d[16][TQ];
  __shared__ int red_k[16][TQ];

  const int tid = threadIdx.x;
  const int q0 = blockIdx.x * TQ;
  const int b = q0 >> 10;       // 1024 queries (h*w) per batch image
  const int hw0 = q0 & 1023;
  const float* hb = hidden + (size_t)b * (C_DIM * 1024) + hw0;

  // stage x tile: xs[c][q] = hidden[b, c, hw0+q]   (contiguous in q)
  for (int idx = tid; idx < C_DIM * TQ; idx += 256) {
    int c = idx >> 6;
    int q = idx & 63;
    xs[c][q] = hb[c * 1024 + q];
  }
  __syncthreads();

  // x_sq per query (fp32; order differences are argmin-neutral)
  {
    int q = tid & 63;
    int part = tid >> 6;
    int cbase = part * 64;
    float s = 0.f;
    for (int c = 0; c < 64; ++c) {
      float v = xs[cbase + c][q];
      s = fmaf(v, v, s);
    }
    xsq_part[part][q] = s;
  }
  __syncthreads();
  if (tid < TQ) {
    xsq[tid] = ((xsq_part[0][tid] + xsq_part[1][tid]) + xsq_part[2][tid]) +
               xsq_part[3][tid];
  }
  __syncthreads();

  const int qt = tid & 15;   // query group (4 queries each)
  const int kt = tid >> 4;   // code group  (4 codes each)

  float xsq_r[4];
#pragma unroll
  for (int i = 0; i < 4; ++i) xsq_r[i] = xsq[qt * 4 + i];

  float bd[4];
  int bk[4];
#pragma unroll
  for (int i = 0; i < 4; ++i) {
    bd[i] = 3.4e38f;
    bk[i] = 0x7fffffff;
  }

  const int kbegin = blockIdx.y * KCHUNK;
  for (int kt0 = kbegin; kt0 < kbegin + KCHUNK; kt0 += TK) {
    __syncthreads();  // protect es from readers of previous tile
    // stage e tile (rows contiguous in HBM; float4 loads)
    for (int idx = tid; idx < TK * (C_DIM / 4); idx += 256) {
      int kk = idx >> 6;
      int c4 = idx & 63;
      float4 v =
          reinterpret_cast<const float4*>(cb + (size_t)(kt0 + kk) * C_DIM)[c4];
      es[kk][c4 * 4 + 0] = v.x;
      es[kk][c4 * 4 + 1] = v.y;
      es[kk][c4 * 4 + 2] = v.z;
      es[kk][c4 * 4 + 3] = v.w;
    }
    __syncthreads();

    float acc[4][4];
#pragma unroll
    for (int i = 0; i < 4; ++i)
#pragma unroll
      for (int j = 0; j < 4; ++j) acc[i][j] = 0.f;

    for (int c4 = 0; c4 < C_DIM; c4 += 4) {
      float4 xv0 = *reinterpret_cast<const float4*>(&xs[c4 + 0][qt * 4]);
      float4 xv1 = *reinterpret_cast<const float4*>(&xs[c4 + 1][qt * 4]);
      float4 xv2 = *reinterpret_cast<const float4*>(&xs[c4 + 2][qt * 4]);
      float4 xv3 = *reinterpret_cast<const float4*>(&xs[c4 + 3][qt * 4]);
      float xq0[4] = {xv0.x, xv0.y, xv0.z, xv0.w};
      float xq1[4] = {xv1.x, xv1.y, xv1.z, xv1.w};
      float xq2[4] = {xv2.x, xv2.y, xv2.z, xv2.w};
      float xq3[4] = {xv3.x, xv3.y, xv3.z, xv3.w};
      float4 ev[4];
#pragma unroll
      for (int j = 0; j < 4; ++j)
        ev[j] = *reinterpret_cast<const float4*>(&es[kt * 4 + j][c4]);
#pragma unroll
      for (int i = 0; i < 4; ++i) {
#pragma unroll
        for (int j = 0; j < 4; ++j) {
          float a = acc[i][j];
          a = fmaf(xq0[i], ev[j].x, a);   // c4+0
          a = fmaf(xq1[i], ev[j].y, a);   // c4+1  (strict ascending c)
          a = fmaf(xq2[i], ev[j].z, a);   // c4+2
          a = fmaf(xq3[i], ev[j].w, a);   // c4+3
          acc[i][j] = a;
        }
      }
    }

#pragma unroll
    for (int j = 0; j < 4; ++j) {
      int k = kt0 + kt * 4 + j;
      float eq = esq[k];
#pragma unroll
      for (int i = 0; i < 4; ++i) {
        float t1 = xsq_r[i] + eq;            // fl(x_sq + e_sq)
        float d = t1 - 2.0f * acc[i][j];     // fl(t1 - 2M) (2M exact)
        if (d < bd[i]) {                     // ascending k -> first-index ties
          bd[i] = d;
          bk[i] = k;
        }
      }
    }
  }

  // cross-thread reduce per query (tie -> smaller index)
#pragma unroll
  for (int i = 0; i < 4; ++i) {
    red_d[kt][qt * 4 + i] = bd[i];
    red_k[kt][qt * 4 + i] = bk[i];
  }
  __syncthreads();
  if (tid < TQ) {
    float d = red_d[0][tid];
    int kb = red_k[0][tid];
    for (int t = 1; t < 16; ++t) {
      float dn = red_d[t][tid];
      int kn = red_k[t][tid];
      if (dn < d || (dn == d && kn < kb)) {
        d = dn;
        kb = kn;
      }
    }
    int q = q0 + tid;
    ws_d[(size_t)q * N_CHUNKS + blockIdx.y] = d;
    ws_k[(size_t)q * N_CHUNKS + blockIdx.y] = kb;
  }
}

// ---------------------------------------------------------------------------
// Reduce the 8 K-chunks per query (tie -> smaller index), emit int32 indices.
// ---------------------------------------------------------------------------
__global__ __launch_bounds__(256) void vq_final_kernel(
    const float* __restrict__ ws_d, const int* __restrict__ ws_k,
    int* __restrict__ out) {
  int n = blockIdx.x * blockDim.x + threadIdx.x;
  if (n >= N_Q) return;
  const float* dp = ws_d + (size_t)n * N_CHUNKS;
  const int* kp = ws_k + (size_t)n * N_CHUNKS;
  float d = dp[0];
  int kb = kp[0];
#pragma unroll
  for (int j = 1; j < N_CHUNKS; ++j) {
    float dn = dp[j];
    int kn = kp[j];
    if (dn < d || (dn == d && kn < kb)) {
      d = dn;
      kb = kn;
    }
  }
  out[n] = kb;
}

extern "C" void kernel_launch(void* const* d_in, const int* in_sizes, int n_in,
                              void* d_out, int out_size, void* d_ws,
                              size_t ws_size, hipStream_t stream) {
  const float* hidden = (const float*)d_in[0];   // (8,1,256,32,32) fp32
  const float* cb = (const float*)d_in[1];       // (16384,256) fp32
  float* esq = (float*)d_ws;                                   // 64 KB
  float* ws_d = (float*)((char*)d_ws + 65536);                 // 256 KB
  int* ws_k = (int*)((char*)d_ws + 65536 + N_Q * N_CHUNKS * 4);// 256 KB
  int* out = (int*)d_out;

  vq_esq_kernel<<<dim3(N_K / 256), dim3(256), 0, stream>>>(cb, esq);
  vq_main_kernel<<<dim3(N_Q / TQ, N_CHUNKS), dim3(256), 0, stream>>>(
      hidden, cb, esq, ws_d, ws_k);
  vq_final_kernel<<<dim3(N_Q / 256), dim3(256), 0, stream>>>(ws_d, ws_k, out);
}